// Round 12
// baseline (370.656 us; speedup 1.0000x reference)
//
#include <hip/hip_runtime.h>

#define NN 100000
#define NE 1600000
#define NG 1024
#define DIN 128
#define D1 100
#define D2 20
#define DSELF 16
#define BN_EPS 1e-5f

#define NB 391      // node buckets of 256 nodes
#define NBLK 782    // edge slice blocks (2048 edges each)
#define EPB 2048
#define RAWCAP 5120 // max edges per bucket (mean 4096, +16 sigma)
#define NAGG2 4000  // agg2 blocks (25 nodes each)
#define NREP 64     // BN partial replicas
#define APITCH 136  // LDS row pitch (bf16) for MFMA A tiles
#define G1BLK 1563  // gemm1 blocks (64 rows each)

typedef unsigned int uint;
typedef unsigned short ushort;
typedef __attribute__((ext_vector_type(8))) short bfv8;
typedef __attribute__((ext_vector_type(4))) float fv4;

__device__ inline float bflo(uint x) { return __uint_as_float(x << 16); }
__device__ inline float bfhi(uint x) { return __uint_as_float(x & 0xffff0000u); }
__device__ inline float bfval(ushort h) { return __uint_as_float(((uint)h) << 16); }
__device__ inline uint packbf2(float a, float b) {  // round-nearest-even bf16 pair
    uint ua = __float_as_uint(a), ub = __float_as_uint(b);
    ua += 0x7fffu + ((ua >> 16) & 1u);
    ub += 0x7fffu + ((ub >> 16) & 1u);
    return (ua >> 16) | (ub & 0xffff0000u);
}
__device__ inline ushort bfr(float x) {
    uint u = __float_as_uint(x);
    u += 0x7fffu + ((u >> 16) & 1u);
    return (ushort)(u >> 16);
}
__device__ inline int wave_scan(int x, int lane) {  // inclusive wave scan
#pragma unroll
    for (int off = 1; off < 64; off <<= 1) {
        int y = __shfl_up(x, off, 64);
        if (lane >= off) x += y;
    }
    return x;
}

// ---- prep: W1/W2/W1p MFMA-fragment tables (W2/W1p hi/lo) + zero pb1r ----
__global__ __launch_bounds__(256) void k_prep(const float* __restrict__ W1,
                                              const float* __restrict__ W2,
                                              const float* __restrict__ W1p,
                                              ushort* __restrict__ W1f,
                                              ushort* __restrict__ W2fh,
                                              ushort* __restrict__ W2fl,
                                              ushort* __restrict__ W1pfh,
                                              ushort* __restrict__ W1pfl,
                                              float* __restrict__ pb1r) {
    int idx = blockIdx.x * 256 + threadIdx.x;
    if (idx < NREP * 200) pb1r[idx] = 0.f;
    if (idx < 14336) {           // W1 [128][100] -> 28 tiles, single bf16
        int tile = idx >> 9, nt = tile >> 2, kk = tile & 3;
        int l = (idx >> 3) & 63, j = idx & 7;
        int k = kk * 32 + (l >> 4) * 8 + j, n = nt * 16 + (l & 15);
        W1f[idx] = bfr((n < 100) ? W1[k * 100 + n] : 0.f);
    } else if (idx < 28672) {    // W2 [100][100] -> 28 tiles, hi/lo
        int x = idx - 14336;
        int tile = x >> 9, nt = tile >> 2, kk = tile & 3;
        int l = (x >> 3) & 63, j = x & 7;
        int k = kk * 32 + (l >> 4) * 8 + j, n = nt * 16 + (l & 15);
        float v = (k < 100 && n < 100) ? W2[k * 100 + n] : 0.f;
        ushort hh = bfr(v);
        W2fh[x] = hh; W2fl[x] = bfr(v - bfval(hh));
    } else if (idx < 32768) {    // W1p [100][20] -> 8 tiles, hi/lo
        int x = idx - 28672;
        int tile = x >> 9, nt = tile >> 2, kk = tile & 3;
        int l = (x >> 3) & 63, j = x & 7;
        int k = kk * 32 + (l >> 4) * 8 + j, n = nt * 16 + (l & 15);
        float v = (k < 100 && n < 20) ? W1p[k * 20 + n] : 0.f;
        ushort hh = bfr(v);
        W1pfh[x] = hh; W1pfl[x] = bfr(v - bfval(hh));
    }
}

// ------- merged: z1bf = bf16(feat @ W1f), pitch-128 + csrA1 histogram ------
__global__ __launch_bounds__(256) void k_gemm1A1(const float* __restrict__ feat,
                                                 const ushort* __restrict__ W1f,
                                                 ushort* __restrict__ z1bf,
                                                 const int* __restrict__ edst,
                                                 int* __restrict__ pbcount) {
    __shared__ __align__(16) char smem[64 * 101 * 4];  // Al (17.4KB) then Ep overlay (25.9KB)
    int t = threadIdx.x;
    int blk = blockIdx.x;
    if (blk >= G1BLK) {  // ---- histogram path (former csrA1) ----
        int hb = blk - G1BLK;
        int* h = (int*)smem;
        for (int i = t; i < NB; i += 256) h[i] = 0;
        __syncthreads();
        int e0 = hb * EPB + t;
#pragma unroll
        for (int i = 0; i < 8; i++) {
            int e = e0 + i * 256;
            if (e < NE) atomicAdd(&h[edst[e] >> 8], 1);
        }
        __syncthreads();
        for (int i = t; i < NB; i += 256) pbcount[i * NBLK + hb] = h[i];
        return;
    }
    // ---- gemm path ----
    ushort* Al = (ushort*)smem;
    int row0 = blk * 64;
#pragma unroll
    for (int i = 0; i < 8; i++) {
        int p = i * 256 + t;
        int r = p >> 5, cq = p & 31;
        int row = row0 + r; if (row >= NN) row = NN - 1;
        float4 v = *(const float4*)(feat + (size_t)row * DIN + cq * 4);
        ushort* dst = Al + r * APITCH + 4 * cq;
        dst[0] = bfr(v.x); dst[1] = bfr(v.y); dst[2] = bfr(v.z); dst[3] = bfr(v.w);
    }
    __syncthreads();
    int w = __builtin_amdgcn_readfirstlane(t >> 6);
    int l = t & 63;
    int m16 = l & 15, quad = l >> 4;
    fv4 acc[7];
#pragma unroll
    for (int nt = 0; nt < 7; nt++) acc[nt] = (fv4){0.f, 0.f, 0.f, 0.f};
    const ushort* arow = Al + (w * 16 + m16) * APITCH;
#pragma unroll
    for (int kk = 0; kk < 4; kk++) {
        int kb = kk * 32 + quad * 8;
        bfv8 a = *(const bfv8*)(arow + kb);
#pragma unroll
        for (int nt = 0; nt < 7; nt++) {
            bfv8 b = *(const bfv8*)(W1f + ((nt * 4 + kk) << 9) + l * 8);
            acc[nt] = __builtin_amdgcn_mfma_f32_16x16x32_bf16(a, b, acc[nt], 0, 0, 0);
        }
    }
    __syncthreads();
    float* Ep = (float*)smem;
#pragma unroll
    for (int nt = 0; nt < 7; nt++) {
        int n = nt * 16 + m16;
        if (n < 100) {
#pragma unroll
            for (int rix = 0; rix < 4; rix++)
                Ep[(w * 16 + quad * 4 + rix) * 101 + n] = acc[nt][rix];
        }
    }
    __syncthreads();
#pragma unroll
    for (int i = 0; i < 13; i++) {
        int p = i * 256 + t;
        if (p < 3200) {
            int rr = p / 50, cc = 2 * (p % 50);
            int row = row0 + rr;
            if (row < NN) {
                float v0 = Ep[rr * 101 + cc], v1 = Ep[rr * 101 + cc + 1];
                *(uint*)(z1bf + (size_t)row * 128 + cc) = packbf2(v0, v1);
            }
        }
    }
}

// S1: per-bucket exclusive scan over 782 blocks via wave shfl (2 barriers)
__global__ __launch_bounds__(1024) void k_csrS1(int* __restrict__ pbcount,
                                                int* __restrict__ btot) {
    __shared__ int wsum[16];
    int t = threadIdx.x, b = blockIdx.x;
    int lane = t & 63, w = t >> 6;
    int v = (t < NBLK) ? pbcount[b * NBLK + t] : 0;
    int x = wave_scan(v, lane);
    if (lane == 63) wsum[w] = x;
    __syncthreads();
    if (w == 0 && lane < 16) {
        int s = wsum[lane];
#pragma unroll
        for (int off = 1; off < 16; off <<= 1) {
            int y = __shfl_up(s, off, 64);
            if (lane >= off) s += y;
        }
        wsum[lane] = s;  // inclusive wave sums
    }
    __syncthreads();
    int incl = x + ((w > 0) ? wsum[w - 1] : 0);
    if (t < NBLK) pbcount[b * NBLK + t] = incl - v;
    if (t == 1023) btot[b] = incl;
}

// ebase: single-block exclusive scan of btot -> ebase_g[0..NB]
__global__ __launch_bounds__(512) void k_ebase(const int* __restrict__ btot,
                                               int* __restrict__ ebase_g) {
    __shared__ int wsum[8];
    int t = threadIdx.x, lane = t & 63, w = t >> 6;
    int v = (t < NB) ? btot[t] : 0;
    int x = wave_scan(v, lane);
    if (lane == 63) wsum[w] = x;
    __syncthreads();
    if (w == 0 && lane < 8) {
        int s = wsum[lane];
#pragma unroll
        for (int off = 1; off < 8; off <<= 1) {
            int y = __shfl_up(s, off, 64);
            if (lane >= off) s += y;
        }
        wsum[lane] = s;
    }
    __syncthreads();
    int incl = x + ((w > 0) ? wsum[w - 1] : 0);
    if (t < NB) ebase_g[t] = incl - v;
    if (t == 511) ebase_g[NB] = incl;
}

// A2: LDS counting-sort by bucket -> CONTIGUOUS run writes (shfl scans, 4 barriers)
__global__ __launch_bounds__(256) void k_csrA2(const int* __restrict__ src,
                                               const int* __restrict__ dst,
                                               const int* __restrict__ pbexcl,
                                               const int* __restrict__ ebase,
                                               uint* __restrict__ gbuf) {
    __shared__ int gb[NB];        // global write base per bucket (this block)
    __shared__ int lo[512];       // local exclusive offset per bucket
    __shared__ int cnt[512];      // hist, then scatter run counters
    __shared__ int wsum4[4];
    __shared__ uint stage[EPB];
    __shared__ ushort bkts[EPB];
    int t = threadIdx.x, blk = blockIdx.x;
    int lane = t & 63, w = t >> 6;
    cnt[t] = 0; cnt[t + 256] = 0;
    __syncthreads();
    // load edges + local histogram
    int e0 = blk * EPB + t;
    uint pv[8]; int bk[8];
#pragma unroll
    for (int i = 0; i < 8; i++) {
        int e = e0 + i * 256;
        if (e < NE) {
            int d = dst[e];
            bk[i] = d >> 8;
            pv[i] = (uint)src[e] | ((uint)(d & 255) << 17);
            atomicAdd(&cnt[bk[i]], 1);
        } else bk[i] = -1;
    }
    if (t < NB)       gb[t]       = ebase[t] + pbexcl[t * NBLK + blk];
    if (t + 256 < NB) gb[t + 256] = ebase[t + 256] + pbexcl[(t + 256) * NBLK + blk];
    __syncthreads();
    // paired shfl scan of cnt[0..511] -> lo (exclusive)
    int a = cnt[2 * t], bb = cnt[2 * t + 1];
    int s = a + bb;
    int x = wave_scan(s, lane);
    if (lane == 63) wsum4[w] = x;
    __syncthreads();
    int woff = 0;
#pragma unroll
    for (int i = 0; i < 4; i++) woff += (i < w) ? wsum4[i] : 0;
    int inclp = x + woff;
    lo[2 * t] = inclp - s;
    lo[2 * t + 1] = inclp - bb;
    cnt[2 * t] = 0; cnt[2 * t + 1] = 0;
    __syncthreads();
    // scatter into LDS sorted by bucket
#pragma unroll
    for (int i = 0; i < 8; i++) {
        if (bk[i] >= 0) {
            int lpos = lo[bk[i]] + atomicAdd(&cnt[bk[i]], 1);
            stage[lpos] = pv[i];
            bkts[lpos] = (ushort)bk[i];
        }
    }
    __syncthreads();
    // contiguous run writes
    int cntb = (blk * EPB + EPB <= NE) ? EPB : (NE - blk * EPB);
    for (int i = t; i < cntb; i += 256) {
        int b = bkts[i];
        gbuf[gb[b] + (i - lo[b])] = stage[i];
    }
}

// B: per-bucket LDS counting sort by local dst -> deg, offs, srcS (shfl scan)
__global__ __launch_bounds__(256) void k_csrB(const uint* __restrict__ gbuf,
                                              const int* __restrict__ ebase,
                                              int* __restrict__ deg,
                                              int* __restrict__ offs,
                                              int* __restrict__ srcS) {
    __shared__ uint raw[RAWCAP];
    __shared__ int srt[RAWCAP];
    __shared__ int cur[256];
    __shared__ int wsum4[4];
    int t = threadIdx.x, b = blockIdx.x;
    int lane = t & 63, w = t >> 6;
    int e0 = ebase[b], e1 = ebase[b + 1];
    int cnt = e1 - e0; if (cnt > RAWCAP) cnt = RAWCAP;
    cur[t] = 0;
    for (int i = t; i < cnt; i += 256) raw[i] = gbuf[e0 + i];
    __syncthreads();
    for (int i = t; i < cnt; i += 256) atomicAdd(&cur[raw[i] >> 17], 1);
    __syncthreads();
    int v = cur[t];
    int x = wave_scan(v, lane);
    if (lane == 63) wsum4[w] = x;
    __syncthreads();
    int woff = 0;
#pragma unroll
    for (int i = 0; i < 4; i++) woff += (i < w) ? wsum4[i] : 0;
    int excl = x + woff - v;
    int node = b * 256 + t;
    if (node < NN) { deg[node] = v; offs[node] = e0 + excl; }
    cur[t] = excl;
    __syncthreads();
    for (int i = t; i < cnt; i += 256) {
        uint p = raw[i];
        int lpos = atomicAdd(&cur[p >> 17], 1);
        srt[lpos] = (int)(p & 0x1FFFFu);
    }
    __syncthreads();
    for (int i = t; i < cnt; i += 256) srcS[e0 + i] = srt[i];
}

// ------- u1(bf16) = z1 + gather-sum; 4 waves/block, 4 nodes/wave (25000 waves) ----
// fused BN1 stats: reg accum -> 4-wave LDS reduce -> 200 atomics/block
__global__ __launch_bounds__(256) void k_agg1(const ushort* __restrict__ z1bf,
                                              const int* __restrict__ offs,
                                              const int* __restrict__ deg,
                                              const int* __restrict__ srcS,
                                              ushort* __restrict__ u1b,
                                              float* __restrict__ pb1r) {
    __shared__ float part[4][200];
    int t = threadIdx.x;
    int wv = __builtin_amdgcn_readfirstlane(t >> 6);
    int l = t & 63;
    bool act = l < 50;
    const ushort* zc = z1bf + 2 * l;
    float S0 = 0.f, S1 = 0.f, Q0 = 0.f, Q1 = 0.f;
    int n0 = blockIdx.x * 16 + wv * 4;  // 6250*16 == NN exactly
#pragma unroll 1
    for (int k = 0; k < 4; k++) {
        int n = n0 + k;
        int d = deg[n], base = offs[n];
        float a0 = 0.f, a1 = 0.f, b0 = 0.f, b1 = 0.f;
        float c0 = 0.f, c1 = 0.f, e0 = 0.f, e1 = 0.f;
        int i = 0;
        for (; i + 8 <= d; i += 8) {
            int s0 = srcS[base + i],     s1 = srcS[base + i + 1];
            int s2 = srcS[base + i + 2], s3 = srcS[base + i + 3];
            int s4 = srcS[base + i + 4], s5 = srcS[base + i + 5];
            int s6 = srcS[base + i + 6], s7 = srcS[base + i + 7];
            if (act) {
                uint x0 = *(const uint*)(zc + (size_t)s0 * 128);
                uint x1 = *(const uint*)(zc + (size_t)s1 * 128);
                uint x2 = *(const uint*)(zc + (size_t)s2 * 128);
                uint x3 = *(const uint*)(zc + (size_t)s3 * 128);
                uint x4 = *(const uint*)(zc + (size_t)s4 * 128);
                uint x5 = *(const uint*)(zc + (size_t)s5 * 128);
                uint x6 = *(const uint*)(zc + (size_t)s6 * 128);
                uint x7 = *(const uint*)(zc + (size_t)s7 * 128);
                a0 += bflo(x0); a1 += bfhi(x0);
                b0 += bflo(x1); b1 += bfhi(x1);
                c0 += bflo(x2); c1 += bfhi(x2);
                e0 += bflo(x3); e1 += bfhi(x3);
                a0 += bflo(x4); a1 += bfhi(x4);
                b0 += bflo(x5); b1 += bfhi(x5);
                c0 += bflo(x6); c1 += bfhi(x6);
                e0 += bflo(x7); e1 += bfhi(x7);
            }
        }
        for (; i + 2 <= d; i += 2) {
            int s0 = srcS[base + i], s1 = srcS[base + i + 1];
            if (act) {
                uint x0 = *(const uint*)(zc + (size_t)s0 * 128);
                uint x1 = *(const uint*)(zc + (size_t)s1 * 128);
                a0 += bflo(x0); a1 += bfhi(x0);
                b0 += bflo(x1); b1 += bfhi(x1);
            }
        }
        if (i < d) {
            int s0 = srcS[base + i];
            if (act) {
                uint x0 = *(const uint*)(zc + (size_t)s0 * 128);
                a0 += bflo(x0); a1 += bfhi(x0);
            }
        }
        if (act) {
            uint xs = *(const uint*)(zc + (size_t)n * 128);
            float r0 = (a0 + b0) + (c0 + e0) + bflo(xs);
            float r1 = (a1 + b1) + (c1 + e1) + bfhi(xs);
            *(uint*)(u1b + (size_t)n * 100 + 2 * l) = packbf2(r0, r1);
            S0 += r0; S1 += r1;
            Q0 = fmaf(r0, r0, Q0); Q1 = fmaf(r1, r1, Q1);
        }
    }
    if (act) {
        part[wv][2 * l] = S0;        part[wv][2 * l + 1] = S1;
        part[wv][100 + 2 * l] = Q0;  part[wv][100 + 2 * l + 1] = Q1;
    }
    __syncthreads();
    if (t < 200) {
        float s = part[0][t] + part[1][t] + part[2][t] + part[3][t];
        atomicAdd(&pb1r[(blockIdx.x & (NREP - 1)) * 200 + t], s);
    }
}

// ------ m2 via MFMA (bf16 hi/lo split, ~fp32 accuracy) ----------
__global__ __launch_bounds__(256) void k_m2(const ushort* __restrict__ u1b,
                                            const float* __restrict__ pb1r,
                                            const float* __restrict__ gamma,
                                            const float* __restrict__ beta,
                                            const ushort* __restrict__ W2fh,
                                            const ushort* __restrict__ W2fl,
                                            const float* __restrict__ b2,
                                            const ushort* __restrict__ W1pfh,
                                            const ushort* __restrict__ W1pfl,
                                            ushort* __restrict__ z2bf,
                                            float* __restrict__ pb2r,
                                            float* __restrict__ hgsum) {
    __shared__ __align__(16) ushort Ah[64 * APITCH];
    __shared__ __align__(16) ushort Alo[64 * APITCH];
    __shared__ float red200[200];
    __shared__ float scW[100], shW[100];
    int t = threadIdx.x;
    if (blockIdx.x == 0) {  // zero BN2 stat replicas + pool sums; stream order covers uses
        for (int i = t; i < NREP * 40; i += 256) pb2r[i] = 0.f;
        for (int i = t; i < NG * D2; i += 256) hgsum[i] = 0.f;
    }
    if (t < 200) {
        float s = 0.f;
#pragma unroll 8
        for (int r = 0; r < NREP; r++) s += pb1r[r * 200 + t];
        red200[t] = s;
    }
    for (int p = t; p < 896; p += 256) {  // zero k-pad cols 100..127
        int r = p / 14, c = 100 + 2 * (p % 14);
        *(uint*)(Ah + r * APITCH + c) = 0u;
        *(uint*)(Alo + r * APITCH + c) = 0u;
    }
    __syncthreads();
    if (t < 100) {
        float S = red200[t], Q = red200[100 + t];
        float mean = S * (1.f / NN);
        float var = Q * (1.f / NN) - mean * mean;
        float inv = rsqrtf(var + BN_EPS);
        float s = gamma[t] * inv;
        scW[t] = s;
        shW[t] = beta[t] - mean * s;
    }
    __syncthreads();
    int row0 = blockIdx.x * 64;
#pragma unroll
    for (int i = 0; i < 13; i++) {
        int p = i * 256 + t;
        if (p < 3200) {
            int r = p / 50, c = 2 * (p % 50);
            int row = row0 + r; if (row >= NN) row = NN - 1;
            uint x = *(const uint*)(u1b + (size_t)row * 100 + c);
            float y0 = fmaxf(bflo(x) * scW[c] + shW[c], 0.f);
            float y1 = fmaxf(bfhi(x) * scW[c + 1] + shW[c + 1], 0.f);
            ushort h0 = bfr(y0), h1 = bfr(y1);
            ushort l0 = bfr(y0 - bfval(h0)), l1 = bfr(y1 - bfval(h1));
            *(uint*)(Ah + r * APITCH + c) = (uint)h0 | ((uint)h1 << 16);
            *(uint*)(Alo + r * APITCH + c) = (uint)l0 | ((uint)l1 << 16);
        }
    }
    __syncthreads();
    int w = __builtin_amdgcn_readfirstlane(t >> 6);
    int l = t & 63;
    int m16 = l & 15, quad = l >> 4;
    fv4 acc[7];
#pragma unroll
    for (int nt = 0; nt < 7; nt++) acc[nt] = (fv4){0.f, 0.f, 0.f, 0.f};
    {
        const ushort* arH = Ah + (w * 16 + m16) * APITCH;
        const ushort* arL = Alo + (w * 16 + m16) * APITCH;
#pragma unroll
        for (int kk = 0; kk < 4; kk++) {
            int kb = kk * 32 + quad * 8;
            bfv8 ah = *(const bfv8*)(arH + kb);
            bfv8 al = *(const bfv8*)(arL + kb);
#pragma unroll
            for (int nt = 0; nt < 7; nt++) {
                int fo = ((nt * 4 + kk) << 9) + l * 8;
                bfv8 bh = *(const bfv8*)(W2fh + fo);
                bfv8 bl = *(const bfv8*)(W2fl + fo);
                acc[nt] = __builtin_amdgcn_mfma_f32_16x16x32_bf16(ah, bh, acc[nt], 0, 0, 0);
                acc[nt] = __builtin_amdgcn_mfma_f32_16x16x32_bf16(ah, bl, acc[nt], 0, 0, 0);
                acc[nt] = __builtin_amdgcn_mfma_f32_16x16x32_bf16(al, bh, acc[nt], 0, 0, 0);
            }
        }
    }
    __syncthreads();
#pragma unroll
    for (int nt = 0; nt < 7; nt++) {
        int n = nt * 16 + m16;
        float bb = (n < 100) ? b2[n] : 0.f;
#pragma unroll
        for (int rix = 0; rix < 4; rix++) {
            int r = w * 16 + quad * 4 + rix;
            float hv = (n < 100) ? fmaxf(acc[nt][rix] + bb, 0.f) : 0.f;
            ushort hh = bfr(hv);
            Ah[r * APITCH + n] = hh;
            Alo[r * APITCH + n] = bfr(hv - bfval(hh));
        }
    }
    __syncthreads();
    fv4 acc2[2];
    acc2[0] = (fv4){0.f, 0.f, 0.f, 0.f};
    acc2[1] = (fv4){0.f, 0.f, 0.f, 0.f};
    {
        const ushort* arH = Ah + (w * 16 + m16) * APITCH;
        const ushort* arL = Alo + (w * 16 + m16) * APITCH;
#pragma unroll
        for (int kk = 0; kk < 4; kk++) {
            int kb = kk * 32 + quad * 8;
            bfv8 ah = *(const bfv8*)(arH + kb);
            bfv8 al = *(const bfv8*)(arL + kb);
#pragma unroll
            for (int nt = 0; nt < 2; nt++) {
                int fo = ((nt * 4 + kk) << 9) + l * 8;
                bfv8 bh = *(const bfv8*)(W1pfh + fo);
                bfv8 bl = *(const bfv8*)(W1pfl + fo);
                acc2[nt] = __builtin_amdgcn_mfma_f32_16x16x32_bf16(ah, bh, acc2[nt], 0, 0, 0);
                acc2[nt] = __builtin_amdgcn_mfma_f32_16x16x32_bf16(ah, bl, acc2[nt], 0, 0, 0);
                acc2[nt] = __builtin_amdgcn_mfma_f32_16x16x32_bf16(al, bh, acc2[nt], 0, 0, 0);
            }
        }
    }
#pragma unroll
    for (int nt = 0; nt < 2; nt++) {
        int c = nt * 16 + m16;
        if (c < 20) {
#pragma unroll
            for (int rix = 0; rix < 4; rix++) {
                int row = row0 + w * 16 + quad * 4 + rix;
                if (row < NN) z2bf[(size_t)row * 32 + c] = bfr(acc2[nt][rix]);
            }
        }
    }
}

// ------- u2 = z2 + gather-sum (unroll 8, fused BN2 replica partials) ---------
__global__ __launch_bounds__(256) void k_agg2(const ushort* __restrict__ z2bf,
                                              const int* __restrict__ offs,
                                              const int* __restrict__ deg,
                                              const int* __restrict__ srcS,
                                              float* __restrict__ u2,
                                              float* __restrict__ pb2r) {
    __shared__ float ls[500], lq[500];
    int t = threadIdx.x;
    int n = blockIdx.x * 25 + t / 10;
    int c2 = 2 * (t % 10);
    float r0 = 0.f, r1 = 0.f;
    if (t < 250 && n < NN) {
        int d = deg[n], base = offs[n];
        const ushort* zc = z2bf + c2;
        float a0 = 0.f, a1 = 0.f, b0 = 0.f, b1 = 0.f;
        float c0 = 0.f, c1 = 0.f, e0 = 0.f, e1 = 0.f;
        int i = 0;
        for (; i + 8 <= d; i += 8) {
            int s0 = srcS[base + i],     s1 = srcS[base + i + 1];
            int s2 = srcS[base + i + 2], s3 = srcS[base + i + 3];
            int s4 = srcS[base + i + 4], s5 = srcS[base + i + 5];
            int s6 = srcS[base + i + 6], s7 = srcS[base + i + 7];
            uint x0 = *(const uint*)(zc + (size_t)s0 * 32);
            uint x1 = *(const uint*)(zc + (size_t)s1 * 32);
            uint x2 = *(const uint*)(zc + (size_t)s2 * 32);
            uint x3 = *(const uint*)(zc + (size_t)s3 * 32);
            uint x4 = *(const uint*)(zc + (size_t)s4 * 32);
            uint x5 = *(const uint*)(zc + (size_t)s5 * 32);
            uint x6 = *(const uint*)(zc + (size_t)s6 * 32);
            uint x7 = *(const uint*)(zc + (size_t)s7 * 32);
            a0 += bflo(x0); a1 += bfhi(x0);
            b0 += bflo(x1); b1 += bfhi(x1);
            c0 += bflo(x2); c1 += bfhi(x2);
            e0 += bflo(x3); e1 += bfhi(x3);
            a0 += bflo(x4); a1 += bfhi(x4);
            b0 += bflo(x5); b1 += bfhi(x5);
            c0 += bflo(x6); c1 += bfhi(x6);
            e0 += bflo(x7); e1 += bfhi(x7);
        }
        for (; i + 2 <= d; i += 2) {
            uint x0 = *(const uint*)(zc + (size_t)srcS[base + i] * 32);
            uint x1 = *(const uint*)(zc + (size_t)srcS[base + i + 1] * 32);
            a0 += bflo(x0); a1 += bfhi(x0);
            b0 += bflo(x1); b1 += bfhi(x1);
        }
        if (i < d) {
            uint x0 = *(const uint*)(zc + (size_t)srcS[base + i] * 32);
            a0 += bflo(x0); a1 += bfhi(x0);
        }
        uint xs = *(const uint*)(zc + (size_t)n * 32);
        r0 = (a0 + b0) + (c0 + e0) + bflo(xs);
        r1 = (a1 + b1) + (c1 + e1) + bfhi(xs);
        *(float2*)(u2 + (size_t)n * D2 + c2) = make_float2(r0, r1);
    }
    if (t < 250) {
        int idx = (t / 10) * 20 + c2;
        ls[idx] = r0;     lq[idx] = r0 * r0;
        ls[idx + 1] = r1; lq[idx + 1] = r1 * r1;
    }
    __syncthreads();
    if (t < 20) {
        float S = 0.f, Q = 0.f;
#pragma unroll
        for (int j = 0; j < 25; j++) { S += ls[j * 20 + t]; Q += lq[j * 20 + t]; }
        int rep = (blockIdx.x & (NREP - 1)) * 40;
        atomicAdd(&pb2r[rep + t], S);
        atomicAdd(&pb2r[rep + 20 + t], Q);
    }
}

// ------ fused: BN2-finalize (per-block) + relu(bn2(u2)) @ g2_W2 + b2 -> relu
//        -> per-graph pooled sums (segmented LDS reduce, sorted n2g) ----
__global__ __launch_bounds__(256) void k_m3p(const float* __restrict__ u2,
                                             const float* __restrict__ pb2r,
                                             const float* __restrict__ gamma,
                                             const float* __restrict__ beta,
                                             const float* __restrict__ W2p,  // [20][20]
                                             const float* __restrict__ b2p,
                                             const int* __restrict__ n2g,
                                             float* __restrict__ hgsum) {
    __shared__ float X[256][21];
    __shared__ int gl[256];
    __shared__ float red40[40], scB[20], shB[20];
    int t = threadIdx.x;
    if (t < 40) {
        float s = 0.f;
#pragma unroll 8
        for (int r = 0; r < NREP; r++) s += pb2r[r * 40 + t];
        red40[t] = s;
    }
    __syncthreads();
    if (t < 20) {
        float S = red40[t], Q = red40[20 + t];
        float mean = S * (1.f / NN);
        float var = Q * (1.f / NN) - mean * mean;
        float inv = rsqrtf(var + BN_EPS);
        float s = gamma[t] * inv;
        scB[t] = s;
        shB[t] = beta[t] - mean * s;
    }
    __syncthreads();
    int row = blockIdx.x * 256 + t;
    bool valid = row < NN;
    gl[t] = valid ? n2g[row] : -1;
    if (valid) {
        float ya[20];
        const float4* up = (const float4*)(u2 + (size_t)row * D2);
#pragma unroll
        for (int i = 0; i < 5; i++) {
            float4 v = up[i];
            ya[4 * i + 0] = fmaxf(v.x * scB[4 * i + 0] + shB[4 * i + 0], 0.f);
            ya[4 * i + 1] = fmaxf(v.y * scB[4 * i + 1] + shB[4 * i + 1], 0.f);
            ya[4 * i + 2] = fmaxf(v.z * scB[4 * i + 2] + shB[4 * i + 2], 0.f);
            ya[4 * i + 3] = fmaxf(v.w * scB[4 * i + 3] + shB[4 * i + 3], 0.f);
        }
#pragma unroll
        for (int j = 0; j < D2; j++) {
            float h = b2p[j];
#pragma unroll
            for (int k = 0; k < D2; k++) h = fmaf(ya[k], W2p[k * D2 + j], h);
            X[t][j] = fmaxf(h, 0.f);
        }
    } else {
#pragma unroll
        for (int j = 0; j < D2; j++) X[t][j] = 0.f;
    }
    __syncthreads();
    if (t < 160) {
        int seg = t / 20, j = t % 20;
        int i0 = seg * 32, i1 = i0 + 32;
        int gprev = -2;
        float acc = 0.f;
        for (int i = i0; i < i1; i++) {
            int gi = gl[i];
            if (gi != gprev) {
                if (gprev >= 0) atomicAdd(&hgsum[gprev * D2 + j], acc);
                gprev = gi; acc = 0.f;
            }
            acc += X[i][j];
        }
        if (gprev >= 0) atomicAdd(&hgsum[gprev * D2 + j], acc);
    }
}

// ---------------- a1 = kron(hgsum/cnt, self_feat) @ fc1_W ----------------
__global__ void k_head1(const float* __restrict__ hgsum, const int* __restrict__ n2g,
                        const float* __restrict__ sf,
                        const float* __restrict__ fc1W, float* __restrict__ a1) {
    int b = blockIdx.x * 8 + threadIdx.x / 32;
    int c = threadIdx.x % 32;
    if (b >= NG) return;
    int lo = 0, hi2 = NN;
    while (lo < hi2) { int mid = (lo + hi2) >> 1; if (n2g[mid] < b) lo = mid + 1; else hi2 = mid; }
    int s0 = lo;
    hi2 = NN;
    while (lo < hi2) { int mid = (lo + hi2) >> 1; if (n2g[mid] < b + 1) lo = mid + 1; else hi2 = mid; }
    float rc = 1.f / fmaxf((float)(lo - s0), 1.f);
    const float* hgb = hgsum + b * D2;
    const float* sfb = sf + b * DSELF;
    float acc = 0.f;
    for (int i = 0; i < D2; i++) {
        float hv = hgb[i] * rc;
#pragma unroll
        for (int j = 0; j < DSELF; j++)
            acc += hv * sfb[j] * fc1W[(i * DSELF + j) * 32 + c];
    }
    a1[b * 32 + c] = acc;
}

// ---------------- single-block head: bn1->relu->fc2->bn2->relu->fc3 ----------
__global__ __launch_bounds__(1024) void k_head2(
    const float* __restrict__ a1, const float* __restrict__ g1,
    const float* __restrict__ be1, const float* __restrict__ fc2W,
    const float* __restrict__ g2, const float* __restrict__ be2,
    const float* __restrict__ fc3W, const float* __restrict__ fc3b,
    float* __restrict__ out) {
    int t = threadIdx.x;
    int lane = t & 63, w = t >> 6;
    __shared__ float s1[16][32], s2[16][32];
    __shared__ float sc[32], sh[32], sc2[8], sh2[8];
    float x[32];
    const float4* ap = (const float4*)(a1 + t * 32);
#pragma unroll
    for (int i = 0; i < 8; i++) {
        float4 v = ap[i];
        x[4 * i] = v.x; x[4 * i + 1] = v.y; x[4 * i + 2] = v.z; x[4 * i + 3] = v.w;
    }
#pragma unroll
    for (int c = 0; c < 32; c++) {
        float v = x[c], q = v * v;
        for (int o = 32; o > 0; o >>= 1) {
            v += __shfl_down(v, o, 64);
            q += __shfl_down(q, o, 64);
        }
        if (lane == 0) { s1[w][c] = v; s2[w][c] = q; }
    }
    __syncthreads();
    if (t < 32) {
        float s = 0.f, q = 0.f;
        for (int ww = 0; ww < 16; ww++) { s += s1[ww][t]; q += s2[ww][t]; }
        float mean = s * (1.f / NG);
        float var = q * (1.f / NG) - mean * mean;
        float inv = rsqrtf(var + BN_EPS);
        float scl = g1[t] * inv;
        sc[t] = scl;
        sh[t] = be1[t] - mean * scl;
    }
    __syncthreads();
#pragma unroll
    for (int c = 0; c < 32; c++) x[c] = fmaxf(x[c] * sc[c] + sh[c], 0.f);
    float y[8];
#pragma unroll
    for (int p = 0; p < 8; p++) {
        float a = 0.f;
#pragma unroll
        for (int c = 0; c < 32; c++) a += x[c] * fc2W[c * 8 + p];
        y[p] = a;
    }
    __syncthreads();
#pragma unroll
    for (int p = 0; p < 8; p++) {
        float v = y[p], q = v * v;
        for (int o = 32; o > 0; o >>= 1) {
            v += __shfl_down(v, o, 64);
            q += __shfl_down(q, o, 64);
        }
        if (lane == 0) { s1[w][p] = v; s2[w][p] = q; }
    }
    __syncthreads();
    if (t < 8) {
        float s = 0.f, q = 0.f;
        for (int ww = 0; ww < 16; ww++) { s += s1[ww][t]; q += s2[ww][t]; }
        float mean = s * (1.f / NG);
        float var = q * (1.f / NG) - mean * mean;
        float inv = rsqrtf(var + BN_EPS);
        float scl = g2[t] * inv;
        sc2[t] = scl;
        sh2[t] = be2[t] - mean * scl;
    }
    __syncthreads();
    float o = fc3b[0];
#pragma unroll
    for (int p = 0; p < 8; p++) {
        float yy = fmaxf(y[p] * sc2[p] + sh2[p], 0.f);
        o += yy * fc3W[p];
    }
    out[t] = o;
}

extern "C" void kernel_launch(void* const* d_in, const int* in_sizes, int n_in,
                              void* d_out, int out_size, void* d_ws, size_t ws_size,
                              hipStream_t stream) {
    const float* feat    = (const float*)d_in[0];
    const float* sf      = (const float*)d_in[1];
    const int*   esrc    = (const int*)d_in[2];
    const int*   edst    = (const int*)d_in[3];
    const int*   n2g     = (const int*)d_in[4];
    const float* g1W1    = (const float*)d_in[5];
    const float* g1gam   = (const float*)d_in[7];
    const float* g1bet   = (const float*)d_in[8];
    const float* g1W2    = (const float*)d_in[9];
    const float* g1b2    = (const float*)d_in[10];
    const float* g2W1    = (const float*)d_in[11];
    const float* g2gam   = (const float*)d_in[13];
    const float* g2bet   = (const float*)d_in[14];
    const float* g2W2    = (const float*)d_in[15];
    const float* g2b2    = (const float*)d_in[16];
    const float* fc1W    = (const float*)d_in[17];
    const float* hbn1g   = (const float*)d_in[19];
    const float* hbn1b   = (const float*)d_in[20];
    const float* fc2W    = (const float*)d_in[21];
    const float* hbn2g   = (const float*)d_in[23];
    const float* hbn2b   = (const float*)d_in[24];
    const float* fc3W    = (const float*)d_in[25];
    const float* fc3b    = (const float*)d_in[26];
    float* out = (float*)d_out;

    char* w = (char*)d_ws;
    size_t off = 0;
    auto alloc = [&](size_t bytes) -> char* {
        char* p = w + off;
        off += (bytes + 15) & ~(size_t)15;
        return p;
    };
    char* regA = alloc((size_t)NN * 128 * 2);
    ushort* z1bf = (ushort*)regA;          // pitch-128 (25.6 MB), dead after agg1
    ushort* z2bf = (ushort*)regA;          // pitch-32, written by m2 over dead z1bf
    float*  u2   = (float*)(regA + 6400000);
    ushort* u1b  = (ushort*)alloc((size_t)NN * 100 * 2);
    int*   pbcnt = (int*)alloc((size_t)NB * NBLK * 4);
    int*   btot  = (int*)alloc(NB * 4);
    int*   ebase = (int*)alloc((NB + 1) * 4);
    uint*  gbuf  = (uint*)alloc((size_t)NE * 4);
    int*   deg   = (int*)alloc(NN * 4);
    int*   offs  = (int*)alloc(NN * 4);
    int*   srcS  = (int*)alloc((size_t)NE * 4);
    float* pb1r  = (float*)alloc((size_t)NREP * 200 * 4);
    float* pb2r  = (float*)alloc((size_t)NREP * 40 * 4);
    ushort* W1f  = (ushort*)alloc(14336 * 2);
    ushort* W2fh = (ushort*)alloc(14336 * 2);
    ushort* W2fl = (ushort*)alloc(14336 * 2);
    ushort* W1pfh = (ushort*)alloc(4096 * 2);
    ushort* W1pfl = (ushort*)alloc(4096 * 2);
    float* hgsum = (float*)alloc((size_t)NG * D2 * 4);
    float* a1    = (float*)alloc(NG * 32 * 4);
    (void)in_sizes; (void)n_in; (void)out_size; (void)ws_size;

    k_prep<<<128, 256, 0, stream>>>(g1W1, g1W2, g2W1, W1f, W2fh, W2fl, W1pfh, W1pfl, pb1r);

    k_gemm1A1<<<G1BLK + NBLK, 256, 0, stream>>>(feat, W1f, z1bf, edst, pbcnt);
    k_csrS1<<<NB, 1024, 0, stream>>>(pbcnt, btot);
    k_ebase<<<1, 512, 0, stream>>>(btot, ebase);
    k_csrA2<<<NBLK, 256, 0, stream>>>(esrc, edst, pbcnt, ebase, gbuf);
    k_csrB<<<NB, 256, 0, stream>>>(gbuf, ebase, deg, offs, srcS);

    k_agg1<<<NN / 16, 256, 0, stream>>>(z1bf, offs, deg, srcS, u1b, pb1r);

    k_m2<<<G1BLK, 256, 0, stream>>>(u1b, pb1r, g1gam, g1bet, W2fh, W2fl, g1b2,
                                    W1pfh, W1pfl, z2bf, pb2r, hgsum);

    k_agg2<<<NAGG2, 256, 0, stream>>>(z2bf, offs, deg, srcS, u2, pb2r);
    k_m3p<<<(NN + 255) / 256, 256, 0, stream>>>(u2, pb2r, g2gam, g2bet, g2W2, g2b2, n2g, hgsum);

    k_head1<<<NG / 8, 256, 0, stream>>>(hgsum, n2g, sf, fc1W, a1);
    k_head2<<<1, 1024, 0, stream>>>(a1, hbn1g, hbn1b, fc2W, hbn2g, hbn2b, fc3W, fc3b, out);
}

// Round 13
// 369.172 us; speedup vs baseline: 1.0040x; 1.0040x over previous
//
#include <hip/hip_runtime.h>

#define NN 100000
#define NE 1600000
#define NG 1024
#define DIN 128
#define D1 100
#define D2 20
#define DSELF 16
#define BN_EPS 1e-5f

#define NB 391      // node buckets of 256 nodes
#define NBLK 782    // edge slice blocks (2048 edges each)
#define EPB 2048
#define RAWCAP 5120 // max edges per bucket (mean 4096, +16 sigma)
#define NAGG2 4000  // agg2 blocks (25 nodes each)
#define NREP 64     // BN partial replicas
#define APITCH 136  // LDS row pitch (bf16) for MFMA A tiles
#define G1BLK 1563  // gemm1 blocks (64 rows each)

typedef unsigned int uint;
typedef unsigned short ushort;
typedef __attribute__((ext_vector_type(8))) short bfv8;
typedef __attribute__((ext_vector_type(4))) float fv4;

__device__ inline float bflo(uint x) { return __uint_as_float(x << 16); }
__device__ inline float bfhi(uint x) { return __uint_as_float(x & 0xffff0000u); }
__device__ inline float bfval(ushort h) { return __uint_as_float(((uint)h) << 16); }
__device__ inline uint packbf2(float a, float b) {  // round-nearest-even bf16 pair
    uint ua = __float_as_uint(a), ub = __float_as_uint(b);
    ua += 0x7fffu + ((ua >> 16) & 1u);
    ub += 0x7fffu + ((ub >> 16) & 1u);
    return (ua >> 16) | (ub & 0xffff0000u);
}
__device__ inline ushort bfr(float x) {
    uint u = __float_as_uint(x);
    u += 0x7fffu + ((u >> 16) & 1u);
    return (ushort)(u >> 16);
}

// ---- prep: W1/W2/W1p MFMA-fragment tables (W2/W1p hi/lo) + zero pb1r ----
__global__ __launch_bounds__(256) void k_prep(const float* __restrict__ W1,
                                              const float* __restrict__ W2,
                                              const float* __restrict__ W1p,
                                              ushort* __restrict__ W1f,
                                              ushort* __restrict__ W2fh,
                                              ushort* __restrict__ W2fl,
                                              ushort* __restrict__ W1pfh,
                                              ushort* __restrict__ W1pfl,
                                              float* __restrict__ pb1r) {
    int idx = blockIdx.x * 256 + threadIdx.x;
    if (idx < NREP * 200) pb1r[idx] = 0.f;
    if (idx < 14336) {           // W1 [128][100] -> 28 tiles, single bf16
        int tile = idx >> 9, nt = tile >> 2, kk = tile & 3;
        int l = (idx >> 3) & 63, j = idx & 7;
        int k = kk * 32 + (l >> 4) * 8 + j, n = nt * 16 + (l & 15);
        W1f[idx] = bfr((n < 100) ? W1[k * 100 + n] : 0.f);
    } else if (idx < 28672) {    // W2 [100][100] -> 28 tiles, hi/lo
        int x = idx - 14336;
        int tile = x >> 9, nt = tile >> 2, kk = tile & 3;
        int l = (x >> 3) & 63, j = x & 7;
        int k = kk * 32 + (l >> 4) * 8 + j, n = nt * 16 + (l & 15);
        float v = (k < 100 && n < 100) ? W2[k * 100 + n] : 0.f;
        ushort hh = bfr(v);
        W2fh[x] = hh; W2fl[x] = bfr(v - bfval(hh));
    } else if (idx < 32768) {    // W1p [100][20] -> 8 tiles, hi/lo
        int x = idx - 28672;
        int tile = x >> 9, nt = tile >> 2, kk = tile & 3;
        int l = (x >> 3) & 63, j = x & 7;
        int k = kk * 32 + (l >> 4) * 8 + j, n = nt * 16 + (l & 15);
        float v = (k < 100 && n < 20) ? W1p[k * 20 + n] : 0.f;
        ushort hh = bfr(v);
        W1pfh[x] = hh; W1pfl[x] = bfr(v - bfval(hh));
    }
}

// ------- merged: z1bf = bf16(feat @ W1f), pitch-128 + csrA1 histogram ------
__global__ __launch_bounds__(256) void k_gemm1A1(const float* __restrict__ feat,
                                                 const ushort* __restrict__ W1f,
                                                 ushort* __restrict__ z1bf,
                                                 const int* __restrict__ edst,
                                                 int* __restrict__ pbcount) {
    __shared__ __align__(16) char smem[64 * 101 * 4];  // Al (17.4KB) then Ep overlay (25.9KB)
    int t = threadIdx.x;
    int blk = blockIdx.x;
    if (blk >= G1BLK) {  // ---- histogram path (former csrA1) ----
        int hb = blk - G1BLK;
        int* h = (int*)smem;
        for (int i = t; i < NB; i += 256) h[i] = 0;
        __syncthreads();
        int e0 = hb * EPB + t;
#pragma unroll
        for (int i = 0; i < 8; i++) {
            int e = e0 + i * 256;
            if (e < NE) atomicAdd(&h[edst[e] >> 8], 1);
        }
        __syncthreads();
        for (int i = t; i < NB; i += 256) pbcount[i * NBLK + hb] = h[i];
        return;
    }
    // ---- gemm path ----
    ushort* Al = (ushort*)smem;
    int row0 = blk * 64;
#pragma unroll
    for (int i = 0; i < 8; i++) {
        int p = i * 256 + t;
        int r = p >> 5, cq = p & 31;
        int row = row0 + r; if (row >= NN) row = NN - 1;
        float4 v = *(const float4*)(feat + (size_t)row * DIN + cq * 4);
        ushort* dst = Al + r * APITCH + 4 * cq;
        dst[0] = bfr(v.x); dst[1] = bfr(v.y); dst[2] = bfr(v.z); dst[3] = bfr(v.w);
    }
    __syncthreads();
    int w = __builtin_amdgcn_readfirstlane(t >> 6);
    int l = t & 63;
    int m16 = l & 15, quad = l >> 4;
    fv4 acc[7];
#pragma unroll
    for (int nt = 0; nt < 7; nt++) acc[nt] = (fv4){0.f, 0.f, 0.f, 0.f};
    const ushort* arow = Al + (w * 16 + m16) * APITCH;
#pragma unroll
    for (int kk = 0; kk < 4; kk++) {
        int kb = kk * 32 + quad * 8;
        bfv8 a = *(const bfv8*)(arow + kb);
#pragma unroll
        for (int nt = 0; nt < 7; nt++) {
            bfv8 b = *(const bfv8*)(W1f + ((nt * 4 + kk) << 9) + l * 8);
            acc[nt] = __builtin_amdgcn_mfma_f32_16x16x32_bf16(a, b, acc[nt], 0, 0, 0);
        }
    }
    __syncthreads();
    float* Ep = (float*)smem;
#pragma unroll
    for (int nt = 0; nt < 7; nt++) {
        int n = nt * 16 + m16;
        if (n < 100) {
#pragma unroll
            for (int rix = 0; rix < 4; rix++)
                Ep[(w * 16 + quad * 4 + rix) * 101 + n] = acc[nt][rix];
        }
    }
    __syncthreads();
#pragma unroll
    for (int i = 0; i < 13; i++) {
        int p = i * 256 + t;
        if (p < 3200) {
            int rr = p / 50, cc = 2 * (p % 50);
            int row = row0 + rr;
            if (row < NN) {
                float v0 = Ep[rr * 101 + cc], v1 = Ep[rr * 101 + cc + 1];
                *(uint*)(z1bf + (size_t)row * 128 + cc) = packbf2(v0, v1);
            }
        }
    }
}

// S1: per-bucket exclusive scan over 782 blocks (in-place) + bucket totals
__global__ __launch_bounds__(1024) void k_csrS1(int* __restrict__ pbcount,
                                                int* __restrict__ btot) {
    __shared__ int s[1024];
    int t = threadIdx.x, b = blockIdx.x;
    int v = (t < NBLK) ? pbcount[b * NBLK + t] : 0;
    s[t] = v;
    __syncthreads();
    for (int off = 1; off < 1024; off <<= 1) {
        int x = (t >= off) ? s[t - off] : 0;
        __syncthreads();
        s[t] += x;
        __syncthreads();
    }
    if (t < NBLK) pbcount[b * NBLK + t] = s[t] - v;
    if (t == 1023) btot[b] = s[t];
}

// A2: ebase scan + LDS counting-sort by bucket -> CONTIGUOUS run writes to gbuf
__global__ __launch_bounds__(256) void k_csrA2(const int* __restrict__ src,
                                               const int* __restrict__ dst,
                                               const int* __restrict__ pbexcl,
                                               const int* __restrict__ btot,
                                               int* __restrict__ ebase_g,
                                               uint* __restrict__ gbuf) {
    __shared__ int gb[NB];       // global write base per bucket (this block)
    __shared__ int lo[NB];       // local exclusive offset per bucket
    __shared__ int cnt[NB];      // hist, then scatter run counters
    __shared__ int sa[512], sb[512];
    __shared__ uint stage[EPB];
    __shared__ ushort bkts[EPB];
    int t = threadIdx.x, blk = blockIdx.x;
    int o0 = (t < NB) ? btot[t] : 0;
    int o1 = (t + 256 < NB) ? btot[t + 256] : 0;
    sa[t] = o0; sa[t + 256] = o1;
    if (t < NB) cnt[t] = 0;
    if (t + 256 < NB) cnt[t + 256] = 0;
    __syncthreads();
    int* sp = sa; int* dp = sb;
    for (int off = 1; off < 512; off <<= 1) {
        dp[t] = sp[t] + ((t >= off) ? sp[t - off] : 0);
        int i2 = t + 256;
        dp[i2] = sp[i2] + ((i2 >= off) ? sp[i2 - off] : 0);
        __syncthreads();
        int* tmp = sp; sp = dp; dp = tmp;
    }
    if (t < NB)       gb[t]       = (sp[t] - o0) + pbexcl[t * NBLK + blk];
    if (t + 256 < NB) gb[t + 256] = (sp[t + 256] - o1) + pbexcl[(t + 256) * NBLK + blk];
    if (blk == 0) {
        if (t < NB)       ebase_g[t]       = sp[t] - o0;
        if (t + 256 < NB) ebase_g[t + 256] = sp[t + 256] - o1;
        if (t == 0)       ebase_g[NB]      = sp[NB - 1];
    }
    __syncthreads();
    int e0 = blk * EPB + t;
    uint pv[8]; int bk[8];
#pragma unroll
    for (int i = 0; i < 8; i++) {
        int e = e0 + i * 256;
        if (e < NE) {
            int d = dst[e];
            bk[i] = d >> 8;
            pv[i] = (uint)src[e] | ((uint)(d & 255) << 17);
            atomicAdd(&cnt[bk[i]], 1);
        } else bk[i] = -1;
    }
    __syncthreads();
    sa[t] = (t < NB) ? cnt[t] : 0;
    sa[t + 256] = (t + 256 < NB) ? cnt[t + 256] : 0;
    __syncthreads();
    sp = sa; dp = sb;
    for (int off = 1; off < 512; off <<= 1) {
        dp[t] = sp[t] + ((t >= off) ? sp[t - off] : 0);
        int i2 = t + 256;
        dp[i2] = sp[i2] + ((i2 >= off) ? sp[i2 - off] : 0);
        __syncthreads();
        int* tmp = sp; sp = dp; dp = tmp;
    }
    if (t < NB)       lo[t]       = sp[t] - cnt[t];
    if (t + 256 < NB) lo[t + 256] = sp[t + 256] - cnt[t + 256];
    __syncthreads();
    if (t < NB) cnt[t] = 0;
    if (t + 256 < NB) cnt[t + 256] = 0;
    __syncthreads();
#pragma unroll
    for (int i = 0; i < 8; i++) {
        if (bk[i] >= 0) {
            int lpos = lo[bk[i]] + atomicAdd(&cnt[bk[i]], 1);
            stage[lpos] = pv[i];
            bkts[lpos] = (ushort)bk[i];
        }
    }
    __syncthreads();
    int cntb = (blk * EPB + EPB <= NE) ? EPB : (NE - blk * EPB);
    for (int i = t; i < cntb; i += 256) {
        int b = bkts[i];
        gbuf[gb[b] + (i - lo[b])] = stage[i];
    }
}

// B: per-bucket LDS counting sort by local dst -> deg, offs, srcS
__global__ __launch_bounds__(256) void k_csrB(const uint* __restrict__ gbuf,
                                              const int* __restrict__ ebase,
                                              int* __restrict__ deg,
                                              int* __restrict__ offs,
                                              int* __restrict__ srcS) {
    __shared__ uint raw[RAWCAP];
    __shared__ int srt[RAWCAP];
    __shared__ int pref[256], cur[256];
    int t = threadIdx.x, b = blockIdx.x;
    int e0 = ebase[b], e1 = ebase[b + 1];
    int cnt = e1 - e0; if (cnt > RAWCAP) cnt = RAWCAP;
    cur[t] = 0;
    for (int i = t; i < cnt; i += 256) raw[i] = gbuf[e0 + i];
    __syncthreads();
    for (int i = t; i < cnt; i += 256) atomicAdd(&cur[raw[i] >> 17], 1);
    __syncthreads();
    int v = cur[t];
    pref[t] = v;
    __syncthreads();
    for (int off = 1; off < 256; off <<= 1) {
        int x = (t >= off) ? pref[t - off] : 0;
        __syncthreads();
        pref[t] += x;
        __syncthreads();
    }
    int excl = pref[t] - v;
    int node = b * 256 + t;
    if (node < NN) { deg[node] = v; offs[node] = e0 + excl; }
    cur[t] = excl;
    __syncthreads();
    for (int i = t; i < cnt; i += 256) {
        uint p = raw[i];
        int lpos = atomicAdd(&cur[p >> 17], 1);
        srt[lpos] = (int)(p & 0x1FFFFu);
    }
    __syncthreads();
    for (int i = t; i < cnt; i += 256) srcS[e0 + i] = srt[i];
}

// ------- u1(bf16) = z1 + gather-sum; 4 waves/block, 4 nodes/wave (25000 waves) ----
// fused BN1 stats: reg accum -> 4-wave LDS reduce -> 200 atomics/block
__global__ __launch_bounds__(256) void k_agg1(const ushort* __restrict__ z1bf,
                                              const int* __restrict__ offs,
                                              const int* __restrict__ deg,
                                              const int* __restrict__ srcS,
                                              ushort* __restrict__ u1b,
                                              float* __restrict__ pb1r) {
    __shared__ float part[4][200];
    int t = threadIdx.x;
    int wv = __builtin_amdgcn_readfirstlane(t >> 6);
    int l = t & 63;
    bool act = l < 50;
    const ushort* zc = z1bf + 2 * l;
    float S0 = 0.f, S1 = 0.f, Q0 = 0.f, Q1 = 0.f;
    int n0 = blockIdx.x * 16 + wv * 4;  // 6250*16 == NN exactly
#pragma unroll 1
    for (int k = 0; k < 4; k++) {
        int n = n0 + k;
        int d = deg[n], base = offs[n];
        float a0 = 0.f, a1 = 0.f, b0 = 0.f, b1 = 0.f;
        float c0 = 0.f, c1 = 0.f, e0 = 0.f, e1 = 0.f;
        int i = 0;
        for (; i + 8 <= d; i += 8) {
            int s0 = srcS[base + i],     s1 = srcS[base + i + 1];
            int s2 = srcS[base + i + 2], s3 = srcS[base + i + 3];
            int s4 = srcS[base + i + 4], s5 = srcS[base + i + 5];
            int s6 = srcS[base + i + 6], s7 = srcS[base + i + 7];
            if (act) {
                uint x0 = *(const uint*)(zc + (size_t)s0 * 128);
                uint x1 = *(const uint*)(zc + (size_t)s1 * 128);
                uint x2 = *(const uint*)(zc + (size_t)s2 * 128);
                uint x3 = *(const uint*)(zc + (size_t)s3 * 128);
                uint x4 = *(const uint*)(zc + (size_t)s4 * 128);
                uint x5 = *(const uint*)(zc + (size_t)s5 * 128);
                uint x6 = *(const uint*)(zc + (size_t)s6 * 128);
                uint x7 = *(const uint*)(zc + (size_t)s7 * 128);
                a0 += bflo(x0); a1 += bfhi(x0);
                b0 += bflo(x1); b1 += bfhi(x1);
                c0 += bflo(x2); c1 += bfhi(x2);
                e0 += bflo(x3); e1 += bfhi(x3);
                a0 += bflo(x4); a1 += bfhi(x4);
                b0 += bflo(x5); b1 += bfhi(x5);
                c0 += bflo(x6); c1 += bfhi(x6);
                e0 += bflo(x7); e1 += bfhi(x7);
            }
        }
        for (; i + 2 <= d; i += 2) {
            int s0 = srcS[base + i], s1 = srcS[base + i + 1];
            if (act) {
                uint x0 = *(const uint*)(zc + (size_t)s0 * 128);
                uint x1 = *(const uint*)(zc + (size_t)s1 * 128);
                a0 += bflo(x0); a1 += bfhi(x0);
                b0 += bflo(x1); b1 += bfhi(x1);
            }
        }
        if (i < d) {
            int s0 = srcS[base + i];
            if (act) {
                uint x0 = *(const uint*)(zc + (size_t)s0 * 128);
                a0 += bflo(x0); a1 += bfhi(x0);
            }
        }
        if (act) {
            uint xs = *(const uint*)(zc + (size_t)n * 128);
            float r0 = (a0 + b0) + (c0 + e0) + bflo(xs);
            float r1 = (a1 + b1) + (c1 + e1) + bfhi(xs);
            *(uint*)(u1b + (size_t)n * 100 + 2 * l) = packbf2(r0, r1);
            S0 += r0; S1 += r1;
            Q0 = fmaf(r0, r0, Q0); Q1 = fmaf(r1, r1, Q1);
        }
    }
    if (act) {
        part[wv][2 * l] = S0;        part[wv][2 * l + 1] = S1;
        part[wv][100 + 2 * l] = Q0;  part[wv][100 + 2 * l + 1] = Q1;
    }
    __syncthreads();
    if (t < 200) {
        float s = part[0][t] + part[1][t] + part[2][t] + part[3][t];
        atomicAdd(&pb1r[(blockIdx.x & (NREP - 1)) * 200 + t], s);
    }
}

// ------ m2 via MFMA (bf16 hi/lo split, ~fp32 accuracy) ----------
__global__ __launch_bounds__(256) void k_m2(const ushort* __restrict__ u1b,
                                            const float* __restrict__ pb1r,
                                            const float* __restrict__ gamma,
                                            const float* __restrict__ beta,
                                            const ushort* __restrict__ W2fh,
                                            const ushort* __restrict__ W2fl,
                                            const float* __restrict__ b2,
                                            const ushort* __restrict__ W1pfh,
                                            const ushort* __restrict__ W1pfl,
                                            ushort* __restrict__ z2bf,
                                            float* __restrict__ pb2r,
                                            float* __restrict__ hgsum) {
    __shared__ __align__(16) ushort Ah[64 * APITCH];
    __shared__ __align__(16) ushort Alo[64 * APITCH];
    __shared__ float red200[200];
    __shared__ float scW[100], shW[100];
    int t = threadIdx.x;
    if (blockIdx.x == 0) {  // zero BN2 stat replicas + pool sums; stream order covers uses
        for (int i = t; i < NREP * 40; i += 256) pb2r[i] = 0.f;
        for (int i = t; i < NG * D2; i += 256) hgsum[i] = 0.f;
    }
    if (t < 200) {
        float s = 0.f;
#pragma unroll 8
        for (int r = 0; r < NREP; r++) s += pb1r[r * 200 + t];
        red200[t] = s;
    }
    for (int p = t; p < 896; p += 256) {  // zero k-pad cols 100..127
        int r = p / 14, c = 100 + 2 * (p % 14);
        *(uint*)(Ah + r * APITCH + c) = 0u;
        *(uint*)(Alo + r * APITCH + c) = 0u;
    }
    __syncthreads();
    if (t < 100) {
        float S = red200[t], Q = red200[100 + t];
        float mean = S * (1.f / NN);
        float var = Q * (1.f / NN) - mean * mean;
        float inv = rsqrtf(var + BN_EPS);
        float s = gamma[t] * inv;
        scW[t] = s;
        shW[t] = beta[t] - mean * s;
    }
    __syncthreads();
    int row0 = blockIdx.x * 64;
#pragma unroll
    for (int i = 0; i < 13; i++) {
        int p = i * 256 + t;
        if (p < 3200) {
            int r = p / 50, c = 2 * (p % 50);
            int row = row0 + r; if (row >= NN) row = NN - 1;
            uint x = *(const uint*)(u1b + (size_t)row * 100 + c);
            float y0 = fmaxf(bflo(x) * scW[c] + shW[c], 0.f);
            float y1 = fmaxf(bfhi(x) * scW[c + 1] + shW[c + 1], 0.f);
            ushort h0 = bfr(y0), h1 = bfr(y1);
            ushort l0 = bfr(y0 - bfval(h0)), l1 = bfr(y1 - bfval(h1));
            *(uint*)(Ah + r * APITCH + c) = (uint)h0 | ((uint)h1 << 16);
            *(uint*)(Alo + r * APITCH + c) = (uint)l0 | ((uint)l1 << 16);
        }
    }
    __syncthreads();
    int w = __builtin_amdgcn_readfirstlane(t >> 6);
    int l = t & 63;
    int m16 = l & 15, quad = l >> 4;
    fv4 acc[7];
#pragma unroll
    for (int nt = 0; nt < 7; nt++) acc[nt] = (fv4){0.f, 0.f, 0.f, 0.f};
    {
        const ushort* arH = Ah + (w * 16 + m16) * APITCH;
        const ushort* arL = Alo + (w * 16 + m16) * APITCH;
#pragma unroll
        for (int kk = 0; kk < 4; kk++) {
            int kb = kk * 32 + quad * 8;
            bfv8 ah = *(const bfv8*)(arH + kb);
            bfv8 al = *(const bfv8*)(arL + kb);
#pragma unroll
            for (int nt = 0; nt < 7; nt++) {
                int fo = ((nt * 4 + kk) << 9) + l * 8;
                bfv8 bh = *(const bfv8*)(W2fh + fo);
                bfv8 bl = *(const bfv8*)(W2fl + fo);
                acc[nt] = __builtin_amdgcn_mfma_f32_16x16x32_bf16(ah, bh, acc[nt], 0, 0, 0);
                acc[nt] = __builtin_amdgcn_mfma_f32_16x16x32_bf16(ah, bl, acc[nt], 0, 0, 0);
                acc[nt] = __builtin_amdgcn_mfma_f32_16x16x32_bf16(al, bh, acc[nt], 0, 0, 0);
            }
        }
    }
    __syncthreads();
#pragma unroll
    for (int nt = 0; nt < 7; nt++) {
        int n = nt * 16 + m16;
        float bb = (n < 100) ? b2[n] : 0.f;
#pragma unroll
        for (int rix = 0; rix < 4; rix++) {
            int r = w * 16 + quad * 4 + rix;
            float hv = (n < 100) ? fmaxf(acc[nt][rix] + bb, 0.f) : 0.f;
            ushort hh = bfr(hv);
            Ah[r * APITCH + n] = hh;
            Alo[r * APITCH + n] = bfr(hv - bfval(hh));
        }
    }
    __syncthreads();
    fv4 acc2[2];
    acc2[0] = (fv4){0.f, 0.f, 0.f, 0.f};
    acc2[1] = (fv4){0.f, 0.f, 0.f, 0.f};
    {
        const ushort* arH = Ah + (w * 16 + m16) * APITCH;
        const ushort* arL = Alo + (w * 16 + m16) * APITCH;
#pragma unroll
        for (int kk = 0; kk < 4; kk++) {
            int kb = kk * 32 + quad * 8;
            bfv8 ah = *(const bfv8*)(arH + kb);
            bfv8 al = *(const bfv8*)(arL + kb);
#pragma unroll
            for (int nt = 0; nt < 2; nt++) {
                int fo = ((nt * 4 + kk) << 9) + l * 8;
                bfv8 bh = *(const bfv8*)(W1pfh + fo);
                bfv8 bl = *(const bfv8*)(W1pfl + fo);
                acc2[nt] = __builtin_amdgcn_mfma_f32_16x16x32_bf16(ah, bh, acc2[nt], 0, 0, 0);
                acc2[nt] = __builtin_amdgcn_mfma_f32_16x16x32_bf16(ah, bl, acc2[nt], 0, 0, 0);
                acc2[nt] = __builtin_amdgcn_mfma_f32_16x16x32_bf16(al, bh, acc2[nt], 0, 0, 0);
            }
        }
    }
#pragma unroll
    for (int nt = 0; nt < 2; nt++) {
        int c = nt * 16 + m16;
        if (c < 20) {
#pragma unroll
            for (int rix = 0; rix < 4; rix++) {
                int row = row0 + w * 16 + quad * 4 + rix;
                if (row < NN) z2bf[(size_t)row * 32 + c] = bfr(acc2[nt][rix]);
            }
        }
    }
}

// ------- u2 = z2 + gather-sum (unroll 8, fused BN2 replica partials) ---------
__global__ __launch_bounds__(256) void k_agg2(const ushort* __restrict__ z2bf,
                                              const int* __restrict__ offs,
                                              const int* __restrict__ deg,
                                              const int* __restrict__ srcS,
                                              float* __restrict__ u2,
                                              float* __restrict__ pb2r) {
    __shared__ float ls[500], lq[500];
    int t = threadIdx.x;
    int n = blockIdx.x * 25 + t / 10;
    int c2 = 2 * (t % 10);
    float r0 = 0.f, r1 = 0.f;
    if (t < 250 && n < NN) {
        int d = deg[n], base = offs[n];
        const ushort* zc = z2bf + c2;
        float a0 = 0.f, a1 = 0.f, b0 = 0.f, b1 = 0.f;
        float c0 = 0.f, c1 = 0.f, e0 = 0.f, e1 = 0.f;
        int i = 0;
        for (; i + 8 <= d; i += 8) {
            int s0 = srcS[base + i],     s1 = srcS[base + i + 1];
            int s2 = srcS[base + i + 2], s3 = srcS[base + i + 3];
            int s4 = srcS[base + i + 4], s5 = srcS[base + i + 5];
            int s6 = srcS[base + i + 6], s7 = srcS[base + i + 7];
            uint x0 = *(const uint*)(zc + (size_t)s0 * 32);
            uint x1 = *(const uint*)(zc + (size_t)s1 * 32);
            uint x2 = *(const uint*)(zc + (size_t)s2 * 32);
            uint x3 = *(const uint*)(zc + (size_t)s3 * 32);
            uint x4 = *(const uint*)(zc + (size_t)s4 * 32);
            uint x5 = *(const uint*)(zc + (size_t)s5 * 32);
            uint x6 = *(const uint*)(zc + (size_t)s6 * 32);
            uint x7 = *(const uint*)(zc + (size_t)s7 * 32);
            a0 += bflo(x0); a1 += bfhi(x0);
            b0 += bflo(x1); b1 += bfhi(x1);
            c0 += bflo(x2); c1 += bfhi(x2);
            e0 += bflo(x3); e1 += bfhi(x3);
            a0 += bflo(x4); a1 += bfhi(x4);
            b0 += bflo(x5); b1 += bfhi(x5);
            c0 += bflo(x6); c1 += bfhi(x6);
            e0 += bflo(x7); e1 += bfhi(x7);
        }
        for (; i + 2 <= d; i += 2) {
            uint x0 = *(const uint*)(zc + (size_t)srcS[base + i] * 32);
            uint x1 = *(const uint*)(zc + (size_t)srcS[base + i + 1] * 32);
            a0 += bflo(x0); a1 += bfhi(x0);
            b0 += bflo(x1); b1 += bfhi(x1);
        }
        if (i < d) {
            uint x0 = *(const uint*)(zc + (size_t)srcS[base + i] * 32);
            a0 += bflo(x0); a1 += bfhi(x0);
        }
        uint xs = *(const uint*)(zc + (size_t)n * 32);
        r0 = (a0 + b0) + (c0 + e0) + bflo(xs);
        r1 = (a1 + b1) + (c1 + e1) + bfhi(xs);
        *(float2*)(u2 + (size_t)n * D2 + c2) = make_float2(r0, r1);
    }
    if (t < 250) {
        int idx = (t / 10) * 20 + c2;
        ls[idx] = r0;     lq[idx] = r0 * r0;
        ls[idx + 1] = r1; lq[idx + 1] = r1 * r1;
    }
    __syncthreads();
    if (t < 20) {
        float S = 0.f, Q = 0.f;
#pragma unroll
        for (int j = 0; j < 25; j++) { S += ls[j * 20 + t]; Q += lq[j * 20 + t]; }
        int rep = (blockIdx.x & (NREP - 1)) * 40;
        atomicAdd(&pb2r[rep + t], S);
        atomicAdd(&pb2r[rep + 20 + t], Q);
    }
}

// ------ fused: BN2-finalize (per-block) + relu(bn2(u2)) @ g2_W2 + b2 -> relu
//        -> per-graph pooled sums (segmented LDS reduce, sorted n2g) ----
__global__ __launch_bounds__(256) void k_m3p(const float* __restrict__ u2,
                                             const float* __restrict__ pb2r,
                                             const float* __restrict__ gamma,
                                             const float* __restrict__ beta,
                                             const float* __restrict__ W2p,  // [20][20]
                                             const float* __restrict__ b2p,
                                             const int* __restrict__ n2g,
                                             float* __restrict__ hgsum) {
    __shared__ float X[256][21];
    __shared__ int gl[256];
    __shared__ float red40[40], scB[20], shB[20];
    int t = threadIdx.x;
    if (t < 40) {
        float s = 0.f;
#pragma unroll 8
        for (int r = 0; r < NREP; r++) s += pb2r[r * 40 + t];
        red40[t] = s;
    }
    __syncthreads();
    if (t < 20) {
        float S = red40[t], Q = red40[20 + t];
        float mean = S * (1.f / NN);
        float var = Q * (1.f / NN) - mean * mean;
        float inv = rsqrtf(var + BN_EPS);
        float s = gamma[t] * inv;
        scB[t] = s;
        shB[t] = beta[t] - mean * s;
    }
    __syncthreads();
    int row = blockIdx.x * 256 + t;
    bool valid = row < NN;
    gl[t] = valid ? n2g[row] : -1;
    if (valid) {
        float ya[20];
        const float4* up = (const float4*)(u2 + (size_t)row * D2);
#pragma unroll
        for (int i = 0; i < 5; i++) {
            float4 v = up[i];
            ya[4 * i + 0] = fmaxf(v.x * scB[4 * i + 0] + shB[4 * i + 0], 0.f);
            ya[4 * i + 1] = fmaxf(v.y * scB[4 * i + 1] + shB[4 * i + 1], 0.f);
            ya[4 * i + 2] = fmaxf(v.z * scB[4 * i + 2] + shB[4 * i + 2], 0.f);
            ya[4 * i + 3] = fmaxf(v.w * scB[4 * i + 3] + shB[4 * i + 3], 0.f);
        }
#pragma unroll
        for (int j = 0; j < D2; j++) {
            float h = b2p[j];
#pragma unroll
            for (int k = 0; k < D2; k++) h = fmaf(ya[k], W2p[k * D2 + j], h);
            X[t][j] = fmaxf(h, 0.f);
        }
    } else {
#pragma unroll
        for (int j = 0; j < D2; j++) X[t][j] = 0.f;
    }
    __syncthreads();
    if (t < 160) {
        int seg = t / 20, j = t % 20;
        int i0 = seg * 32, i1 = i0 + 32;
        int gprev = -2;
        float acc = 0.f;
        for (int i = i0; i < i1; i++) {
            int gi = gl[i];
            if (gi != gprev) {
                if (gprev >= 0) atomicAdd(&hgsum[gprev * D2 + j], acc);
                gprev = gi; acc = 0.f;
            }
            acc += X[i][j];
        }
        if (gprev >= 0) atomicAdd(&hgsum[gprev * D2 + j], acc);
    }
}

// ---------------- a1 = kron(hgsum/cnt, self_feat) @ fc1_W ----------------
__global__ void k_head1(const float* __restrict__ hgsum, const int* __restrict__ n2g,
                        const float* __restrict__ sf,
                        const float* __restrict__ fc1W, float* __restrict__ a1) {
    int b = blockIdx.x * 8 + threadIdx.x / 32;
    int c = threadIdx.x % 32;
    if (b >= NG) return;
    int lo = 0, hi2 = NN;
    while (lo < hi2) { int mid = (lo + hi2) >> 1; if (n2g[mid] < b) lo = mid + 1; else hi2 = mid; }
    int s0 = lo;
    hi2 = NN;
    while (lo < hi2) { int mid = (lo + hi2) >> 1; if (n2g[mid] < b + 1) lo = mid + 1; else hi2 = mid; }
    float rc = 1.f / fmaxf((float)(lo - s0), 1.f);
    const float* hgb = hgsum + b * D2;
    const float* sfb = sf + b * DSELF;
    float acc = 0.f;
    for (int i = 0; i < D2; i++) {
        float hv = hgb[i] * rc;
#pragma unroll
        for (int j = 0; j < DSELF; j++)
            acc += hv * sfb[j] * fc1W[(i * DSELF + j) * 32 + c];
    }
    a1[b * 32 + c] = acc;
}

// ---------------- single-block head: bn1->relu->fc2->bn2->relu->fc3 ----------
__global__ __launch_bounds__(1024) void k_head2(
    const float* __restrict__ a1, const float* __restrict__ g1,
    const float* __restrict__ be1, const float* __restrict__ fc2W,
    const float* __restrict__ g2, const float* __restrict__ be2,
    const float* __restrict__ fc3W, const float* __restrict__ fc3b,
    float* __restrict__ out) {
    int t = threadIdx.x;
    int lane = t & 63, w = t >> 6;
    __shared__ float s1[16][32], s2[16][32];
    __shared__ float sc[32], sh[32], sc2[8], sh2[8];
    float x[32];
    const float4* ap = (const float4*)(a1 + t * 32);
#pragma unroll
    for (int i = 0; i < 8; i++) {
        float4 v = ap[i];
        x[4 * i] = v.x; x[4 * i + 1] = v.y; x[4 * i + 2] = v.z; x[4 * i + 3] = v.w;
    }
#pragma unroll
    for (int c = 0; c < 32; c++) {
        float v = x[c], q = v * v;
        for (int o = 32; o > 0; o >>= 1) {
            v += __shfl_down(v, o, 64);
            q += __shfl_down(q, o, 64);
        }
        if (lane == 0) { s1[w][c] = v; s2[w][c] = q; }
    }
    __syncthreads();
    if (t < 32) {
        float s = 0.f, q = 0.f;
        for (int ww = 0; ww < 16; ww++) { s += s1[ww][t]; q += s2[ww][t]; }
        float mean = s * (1.f / NG);
        float var = q * (1.f / NG) - mean * mean;
        float inv = rsqrtf(var + BN_EPS);
        float scl = g1[t] * inv;
        sc[t] = scl;
        sh[t] = be1[t] - mean * scl;
    }
    __syncthreads();
#pragma unroll
    for (int c = 0; c < 32; c++) x[c] = fmaxf(x[c] * sc[c] + sh[c], 0.f);
    float y[8];
#pragma unroll
    for (int p = 0; p < 8; p++) {
        float a = 0.f;
#pragma unroll
        for (int c = 0; c < 32; c++) a += x[c] * fc2W[c * 8 + p];
        y[p] = a;
    }
    __syncthreads();
#pragma unroll
    for (int p = 0; p < 8; p++) {
        float v = y[p], q = v * v;
        for (int o = 32; o > 0; o >>= 1) {
            v += __shfl_down(v, o, 64);
            q += __shfl_down(q, o, 64);
        }
        if (lane == 0) { s1[w][p] = v; s2[w][p] = q; }
    }
    __syncthreads();
    if (t < 8) {
        float s = 0.f, q = 0.f;
        for (int ww = 0; ww < 16; ww++) { s += s1[ww][t]; q += s2[ww][t]; }
        float mean = s * (1.f / NG);
        float var = q * (1.f / NG) - mean * mean;
        float inv = rsqrtf(var + BN_EPS);
        float scl = g2[t] * inv;
        sc2[t] = scl;
        sh2[t] = be2[t] - mean * scl;
    }
    __syncthreads();
    float o = fc3b[0];
#pragma unroll
    for (int p = 0; p < 8; p++) {
        float yy = fmaxf(y[p] * sc2[p] + sh2[p], 0.f);
        o += yy * fc3W[p];
    }
    out[t] = o;
}

extern "C" void kernel_launch(void* const* d_in, const int* in_sizes, int n_in,
                              void* d_out, int out_size, void* d_ws, size_t ws_size,
                              hipStream_t stream) {
    const float* feat    = (const float*)d_in[0];
    const float* sf      = (const float*)d_in[1];
    const int*   esrc    = (const int*)d_in[2];
    const int*   edst    = (const int*)d_in[3];
    const int*   n2g     = (const int*)d_in[4];
    const float* g1W1    = (const float*)d_in[5];
    const float* g1gam   = (const float*)d_in[7];
    const float* g1bet   = (const float*)d_in[8];
    const float* g1W2    = (const float*)d_in[9];
    const float* g1b2    = (const float*)d_in[10];
    const float* g2W1    = (const float*)d_in[11];
    const float* g2gam   = (const float*)d_in[13];
    const float* g2bet   = (const float*)d_in[14];
    const float* g2W2    = (const float*)d_in[15];
    const float* g2b2    = (const float*)d_in[16];
    const float* fc1W    = (const float*)d_in[17];
    const float* hbn1g   = (const float*)d_in[19];
    const float* hbn1b   = (const float*)d_in[20];
    const float* fc2W    = (const float*)d_in[21];
    const float* hbn2g   = (const float*)d_in[23];
    const float* hbn2b   = (const float*)d_in[24];
    const float* fc3W    = (const float*)d_in[25];
    const float* fc3b    = (const float*)d_in[26];
    float* out = (float*)d_out;

    char* w = (char*)d_ws;
    size_t off = 0;
    auto alloc = [&](size_t bytes) -> char* {
        char* p = w + off;
        off += (bytes + 15) & ~(size_t)15;
        return p;
    };
    char* regA = alloc((size_t)NN * 128 * 2);
    ushort* z1bf = (ushort*)regA;          // pitch-128 (25.6 MB), dead after agg1
    ushort* z2bf = (ushort*)regA;          // pitch-32, written by m2 over dead z1bf
    float*  u2   = (float*)(regA + 6400000);
    ushort* u1b  = (ushort*)alloc((size_t)NN * 100 * 2);
    int*   pbcnt = (int*)alloc((size_t)NB * NBLK * 4);
    int*   btot  = (int*)alloc(NB * 4);
    int*   ebase = (int*)alloc((NB + 1) * 4);
    uint*  gbuf  = (uint*)alloc((size_t)NE * 4);
    int*   deg   = (int*)alloc(NN * 4);
    int*   offs  = (int*)alloc(NN * 4);
    int*   srcS  = (int*)alloc((size_t)NE * 4);
    float* pb1r  = (float*)alloc((size_t)NREP * 200 * 4);
    float* pb2r  = (float*)alloc((size_t)NREP * 40 * 4);
    ushort* W1f  = (ushort*)alloc(14336 * 2);
    ushort* W2fh = (ushort*)alloc(14336 * 2);
    ushort* W2fl = (ushort*)alloc(14336 * 2);
    ushort* W1pfh = (ushort*)alloc(4096 * 2);
    ushort* W1pfl = (ushort*)alloc(4096 * 2);
    float* hgsum = (float*)alloc((size_t)NG * D2 * 4);
    float* a1    = (float*)alloc(NG * 32 * 4);
    (void)in_sizes; (void)n_in; (void)out_size; (void)ws_size;

    k_prep<<<128, 256, 0, stream>>>(g1W1, g1W2, g2W1, W1f, W2fh, W2fl, W1pfh, W1pfl, pb1r);

    k_gemm1A1<<<G1BLK + NBLK, 256, 0, stream>>>(feat, W1f, z1bf, edst, pbcnt);
    k_csrS1<<<NB, 1024, 0, stream>>>(pbcnt, btot);
    k_csrA2<<<NBLK, 256, 0, stream>>>(esrc, edst, pbcnt, btot, ebase, gbuf);
    k_csrB<<<NB, 256, 0, stream>>>(gbuf, ebase, deg, offs, srcS);

    k_agg1<<<NN / 16, 256, 0, stream>>>(z1bf, offs, deg, srcS, u1b, pb1r);

    k_m2<<<G1BLK, 256, 0, stream>>>(u1b, pb1r, g1gam, g1bet, W2fh, W2fl, g1b2,
                                    W1pfh, W1pfl, z2bf, pb2r, hgsum);

    k_agg2<<<NAGG2, 256, 0, stream>>>(z2bf, offs, deg, srcS, u2, pb2r);
    k_m3p<<<(NN + 255) / 256, 256, 0, stream>>>(u2, pb2r, g2gam, g2bet, g2W2, g2b2, n2g, hgsum);

    k_head1<<<NG / 8, 256, 0, stream>>>(hgsum, n2g, sf, fc1W, a1);
    k_head2<<<1, 1024, 0, stream>>>(a1, hbn1g, hbn1b, fc2W, hbn2g, hbn2b, fc3W, fc3b, out);
}